// Round 10
// baseline (106.723 us; speedup 1.0000x reference)
//
#include <hip/hip_runtime.h>

// MemoryAugmentation: value[b,c] = softmax_m(x[b,c] . mem[m]) . mem
// B*C = 8192 rows, H*W = 7744 (= 1936 float4), M = 10 slots.
//
// R10: cut mem L2 re-read traffic (72% of R3's 1.77 GB L2 stream) by
// covering 8 rows/block at only ~80 VGPR: each WAVE owns 2 rows over the
// FULL iv range (acc[2][10]=20 regs), 4 waves own different rows, and all
// waves walk the same 64-wide iv chunk in lockstep (__syncthreads per
// chunk) so their identical mem loads dedup in L1 (10KB window << 32KB L1).
// mem L2 traffic: 1.27 GB -> 0.635 GB. Softmax is wave-local (butterfly,
// then every lane computes it redundantly) - no LDS, no extra barriers.
// Register discipline: acc20+mv40+xv8+addr ~= 80 regs; no double-buffering.

#define RPW     2             // rows per wave
#define NWAVES  4
#define ROWS_PB (RPW * NWAVES)  // 8 rows per block
#define NM      10
#define NVEC    1936          // 7744 / 4 float4 per row
#define NCHUNK  31            // ceil(1936/64)
#define THREADS 256

typedef float f32x4 __attribute__((ext_vector_type(4)));

__global__ __launch_bounds__(THREADS)
void memaug_kernel(const float* __restrict__ x,
                   const float* __restrict__ mem,
                   float* __restrict__ out)
{
    const int tid  = threadIdx.x;
    const int lane = tid & 63;
    const int wv   = tid >> 6;
    const long rowbase = (long)blockIdx.x * ROWS_PB + (long)wv * RPW;

    const f32x4* __restrict__ m4 = (const f32x4*)mem;
    const f32x4* __restrict__ xr = (const f32x4*)x + rowbase * NVEC;
    f32x4* __restrict__ orow     = (f32x4*)out + rowbase * NVEC;

    // ---------------- Phase 1: per-wave scores over full iv range ----------------
    float acc[RPW][NM];
#pragma unroll
    for (int j = 0; j < RPW; ++j)
#pragma unroll
        for (int m = 0; m < NM; ++m) acc[j][m] = 0.f;

    for (int c = 0; c < NCHUNK; ++c) {
        const int iv = c * 64 + lane;
        const bool ok = iv < NVEC;   // only chunk 30 is partial

        f32x4 xv[RPW], mv[NM];
        if (ok) {
#pragma unroll
            for (int j = 0; j < RPW; ++j)
                xv[j] = xr[j * NVEC + iv];
#pragma unroll
            for (int m = 0; m < NM; ++m)
                mv[m] = m4[m * NVEC + iv];
        } else {
            // zero xv so stale/garbage mv contributes 0 (mv stale = finite,
            // chunk 30 follows 30 full chunks)
#pragma unroll
            for (int j = 0; j < RPW; ++j) xv[j] = (f32x4)(0.f);
        }
#pragma unroll
        for (int m = 0; m < NM; ++m) {
#pragma unroll
            for (int j = 0; j < RPW; ++j) {
                acc[j][m] += xv[j].x * mv[m].x + xv[j].y * mv[m].y
                           + xv[j].z * mv[m].z + xv[j].w * mv[m].w;
            }
        }
        __syncthreads();   // keep waves chunk-aligned for L1 mv dedup
    }

    // ---------------- wave butterfly: all lanes get full sums ----------------
#pragma unroll
    for (int j = 0; j < RPW; ++j)
#pragma unroll
        for (int m = 0; m < NM; ++m) {
            float v = acc[j][m];
#pragma unroll
            for (int off = 32; off > 0; off >>= 1)
                v += __shfl_xor(v, off, 64);
            acc[j][m] = v;
        }

    // ---------------- softmax (every lane redundantly; no LDS) ----------------
    float p[RPW][NM];
#pragma unroll
    for (int j = 0; j < RPW; ++j) {
        float mx = -1e30f;
#pragma unroll
        for (int m = 0; m < NM; ++m) mx = fmaxf(mx, acc[j][m]);
        float sum = 0.f;
#pragma unroll
        for (int m = 0; m < NM; ++m) { p[j][m] = expf(acc[j][m] - mx); sum += p[j][m]; }
        const float inv = 1.f / sum;
#pragma unroll
        for (int m = 0; m < NM; ++m) p[j][m] *= inv;
    }

    // ---------------- Phase 2: out rows = p . mem ----------------
    for (int c = 0; c < NCHUNK; ++c) {
        const int iv = c * 64 + lane;
        const bool ok = iv < NVEC;

        if (ok) {
            f32x4 mv[NM];
#pragma unroll
            for (int m = 0; m < NM; ++m)
                mv[m] = m4[m * NVEC + iv];

            f32x4 ov[RPW];
#pragma unroll
            for (int j = 0; j < RPW; ++j) ov[j] = (f32x4)(0.f);
#pragma unroll
            for (int m = 0; m < NM; ++m) {
#pragma unroll
                for (int j = 0; j < RPW; ++j) {
                    ov[j].x += p[j][m] * mv[m].x;
                    ov[j].y += p[j][m] * mv[m].y;
                    ov[j].z += p[j][m] * mv[m].z;
                    ov[j].w += p[j][m] * mv[m].w;
                }
            }
#pragma unroll
            for (int j = 0; j < RPW; ++j)
                __builtin_nontemporal_store(ov[j], &orow[j * NVEC + iv]);
        }
        __syncthreads();   // keep waves chunk-aligned for L1 mv dedup
    }
}

extern "C" void kernel_launch(void* const* d_in, const int* in_sizes, int n_in,
                              void* d_out, int out_size, void* d_ws, size_t ws_size,
                              hipStream_t stream) {
    const float* x   = (const float*)d_in[0];   // [32,256,88,88] f32
    const float* mem = (const float*)d_in[1];   // [10,88,88] f32
    float* out       = (float*)d_out;           // [32,256,88,88] f32

    const int rows   = 32 * 256;                // 8192
    const int blocks = rows / ROWS_PB;          // 1024

    memaug_kernel<<<blocks, THREADS, 0, stream>>>(x, mem, out);
}